// Round 5
// baseline (451.043 us; speedup 1.0000x reference)
//
#include <hip/hip_runtime.h>
#include <math.h>

#define N_NODES 100000
#define N_EDGES 1600000
#define D_FEAT 64
#define EPS 1e-7f

__device__ __forceinline__ unsigned short f32_to_bf16_rtne(float f) {
    unsigned u = __float_as_uint(f);
    unsigned rounding = 0x7FFFu + ((u >> 16) & 1u);
    return (unsigned short)((u + rounding) >> 16);
}
__device__ __forceinline__ float bf16lo_to_f32(unsigned u) {   // low 16 bits
    return __uint_as_float(u << 16);
}
__device__ __forceinline__ float bf16hi_to_f32(unsigned u) {   // high 16 bits
    return __uint_as_float(u & 0xFFFF0000u);
}
__device__ __forceinline__ float4 f4fma(float4 acc, float p, float4 a) {
    acc.x += p * a.x; acc.y += p * a.y; acc.z += p * a.z; acc.w += p * a.w;
    return acc;
}

// Zero segsum[N] and cnt[N].
__global__ void init_kernel(float* __restrict__ segsum, unsigned* __restrict__ cnt) {
    int i = blockIdx.x * blockDim.x + threadIdx.x;
    if (i < N_NODES) { cnt[i] = 0u; segsum[i] = 0.0f; }
}

// 16 lanes per node: nrm[i] = ||x[i]|| AND xh[i] = bf16(x[i]) (packed 2/uint).
__global__ void norm_cvt_kernel(const float4* __restrict__ x4, float* __restrict__ nrm,
                                uint2* __restrict__ xh2) {
    int tid = blockIdx.x * blockDim.x + threadIdx.x;
    int node = tid >> 4;
    int lane = tid & 15;
    if (node >= N_NODES) return;
    float4 v = x4[(size_t)node * 16 + lane];
    uint2 h;
    h.x = (unsigned)f32_to_bf16_rtne(v.x) | ((unsigned)f32_to_bf16_rtne(v.y) << 16);
    h.y = (unsigned)f32_to_bf16_rtne(v.z) | ((unsigned)f32_to_bf16_rtne(v.w) << 16);
    xh2[(size_t)node * 16 + lane] = h;
    float s = v.x * v.x + v.y * v.y + v.z * v.z + v.w * v.w;
    s += __shfl_xor(s, 1);
    s += __shfl_xor(s, 2);
    s += __shfl_xor(s, 4);
    s += __shfl_xor(s, 8);
    if (lane == 0) nrm[node] = sqrtf(s);
}

// Histogram of col.
__global__ void hist_kernel(const int* __restrict__ col, unsigned* __restrict__ cnt) {
    int e = blockIdx.x * blockDim.x + threadIdx.x;
    if (e >= N_EDGES) return;
    atomicAdd(&cnt[col[e]], 1u);
}

// ---- hierarchical exclusive scan over cnt[0..N) -> offs, cursor ----
#define SCAN_B 256
__global__ void scan1_kernel(const unsigned* __restrict__ cnt, unsigned* __restrict__ incl,
                             unsigned* __restrict__ bsum) {
    __shared__ unsigned sh[SCAN_B];
    int i = blockIdx.x * SCAN_B + threadIdx.x;
    unsigned v = (i < N_NODES) ? cnt[i] : 0u;
    sh[threadIdx.x] = v;
    __syncthreads();
    for (int off = 1; off < SCAN_B; off <<= 1) {
        unsigned u = (threadIdx.x >= off) ? sh[threadIdx.x - off] : 0u;
        __syncthreads();
        sh[threadIdx.x] += u;
        __syncthreads();
    }
    if (i < N_NODES) incl[i] = sh[threadIdx.x];
    if (threadIdx.x == SCAN_B - 1) bsum[blockIdx.x] = sh[SCAN_B - 1];
}

__global__ void scan2_kernel(unsigned* __restrict__ bsum, int nblocks) {
    __shared__ unsigned sh[512];
    int t = threadIdx.x;
    unsigned v = (t < nblocks) ? bsum[t] : 0u;
    sh[t] = v;
    __syncthreads();
    for (int off = 1; off < 512; off <<= 1) {
        unsigned u = (t >= off) ? sh[t - off] : 0u;
        __syncthreads();
        sh[t] += u;
        __syncthreads();
    }
    if (t < nblocks) bsum[t] = sh[t] - v;  // exclusive
}

__global__ void scan3_kernel(const unsigned* __restrict__ cnt, const unsigned* __restrict__ incl,
                             const unsigned* __restrict__ bsum, unsigned* __restrict__ offs,
                             unsigned* __restrict__ cursor) {
    int i = blockIdx.x * SCAN_B + threadIdx.x;
    if (i < N_NODES) {
        unsigned o = bsum[blockIdx.x] + incl[i] - cnt[i];
        offs[i] = o;
        cursor[i] = o;
    } else if (i == N_NODES) {
        offs[N_NODES] = N_EDGES;
    }
}

// One thread per edge: bin row id into col-sorted srow (the only scatter).
__global__ void place_kernel(const int* __restrict__ row, const int* __restrict__ col,
                             unsigned* __restrict__ cursor, unsigned* __restrict__ srow) {
    int e = blockIdx.x * blockDim.x + threadIdx.x;
    if (e >= N_EDGES) return;
    int r = row[e], c = col[e];
    unsigned pos = atomicAdd(&cursor[c], 1u);
    __builtin_nontemporal_store((unsigned)r, &srow[pos]);
}

// 16 lanes per node c over its CSR range: one random bf16 gather per edge,
// c-side register-resident, sequential sex writes, segsum atomics (L2-resident).
__global__ void sim_csr_kernel(const uint2* __restrict__ xh2, const unsigned* __restrict__ offs,
                               const unsigned* __restrict__ srow, const float* __restrict__ nrm,
                               const float* __restrict__ beta_p, float* __restrict__ segsum,
                               float* __restrict__ sex) {
    int tid = blockIdx.x * blockDim.x + threadIdx.x;
    int node = tid >> 4;
    int lane = tid & 15;
    if (node >= N_NODES) return;
    uint2 hc = xh2[(size_t)node * 16 + lane];
    float c0 = bf16lo_to_f32(hc.x), c1 = bf16hi_to_f32(hc.x);
    float c2 = bf16lo_to_f32(hc.y), c3 = bf16hi_to_f32(hc.y);
    float nc = nrm[node];
    float beta = beta_p[0];
    int i = (int)offs[node];
    int end = (int)offs[node + 1];
    for (; i + 1 < end; i += 2) {
        unsigned r0 = srow[i], r1 = srow[i + 1];
        uint2 a0 = xh2[(size_t)r0 * 16 + lane];
        uint2 a1 = xh2[(size_t)r1 * 16 + lane];
        float nr0 = nrm[r0], nr1 = nrm[r1];
        float s0 = bf16lo_to_f32(a0.x) * c0 + bf16hi_to_f32(a0.x) * c1
                 + bf16lo_to_f32(a0.y) * c2 + bf16hi_to_f32(a0.y) * c3;
        float s1 = bf16lo_to_f32(a1.x) * c0 + bf16hi_to_f32(a1.x) * c1
                 + bf16lo_to_f32(a1.y) * c2 + bf16hi_to_f32(a1.y) * c3;
        s0 += __shfl_xor(s0, 1);  s1 += __shfl_xor(s1, 1);
        s0 += __shfl_xor(s0, 2);  s1 += __shfl_xor(s1, 2);
        s0 += __shfl_xor(s0, 4);  s1 += __shfl_xor(s1, 4);
        s0 += __shfl_xor(s0, 8);  s1 += __shfl_xor(s1, 8);
        if (lane == 0) {
            float ex0 = expf(beta * (s0 / (nr0 * nc + EPS)));
            float ex1 = expf(beta * (s1 / (nr1 * nc + EPS)));
            sex[i] = ex0;
            sex[i + 1] = ex1;
            atomicAdd(&segsum[r0], ex0);
            atomicAdd(&segsum[r1], ex1);
        }
    }
    if (i < end) {
        unsigned r0 = srow[i];
        uint2 a0 = xh2[(size_t)r0 * 16 + lane];
        float nr0 = nrm[r0];
        float s0 = bf16lo_to_f32(a0.x) * c0 + bf16hi_to_f32(a0.x) * c1
                 + bf16lo_to_f32(a0.y) * c2 + bf16hi_to_f32(a0.y) * c3;
        s0 += __shfl_xor(s0, 1);
        s0 += __shfl_xor(s0, 2);
        s0 += __shfl_xor(s0, 4);
        s0 += __shfl_xor(s0, 8);
        if (lane == 0) {
            float ex0 = expf(beta * (s0 / (nr0 * nc + EPS)));
            sex[i] = ex0;
            atomicAdd(&segsum[r0], ex0);
        }
    }
}

// 16 lanes per node: out[n] = sum over incoming edges of (ex/segsum[row]) * x[row].
__global__ void gather_kernel(const float4* __restrict__ x4, const unsigned* __restrict__ offs,
                              const unsigned* __restrict__ srow, const float* __restrict__ sex,
                              const float* __restrict__ segsum, float4* __restrict__ out4) {
    int tid = blockIdx.x * blockDim.x + threadIdx.x;
    int node = tid >> 4;
    int lane = tid & 15;
    if (node >= N_NODES) return;
    int i = (int)offs[node];
    int end = (int)offs[node + 1];
    float4 acc = make_float4(0.f, 0.f, 0.f, 0.f);
    for (; i + 3 < end; i += 4) {
        unsigned r0 = srow[i],     r1 = srow[i + 1];
        unsigned r2 = srow[i + 2], r3 = srow[i + 3];
        float p0 = sex[i]     / segsum[r0];
        float p1 = sex[i + 1] / segsum[r1];
        float p2 = sex[i + 2] / segsum[r2];
        float p3 = sex[i + 3] / segsum[r3];
        float4 a0 = x4[(size_t)r0 * 16 + lane];
        float4 a1 = x4[(size_t)r1 * 16 + lane];
        float4 a2 = x4[(size_t)r2 * 16 + lane];
        float4 a3 = x4[(size_t)r3 * 16 + lane];
        acc = f4fma(acc, p0, a0);
        acc = f4fma(acc, p1, a1);
        acc = f4fma(acc, p2, a2);
        acc = f4fma(acc, p3, a3);
    }
    for (; i < end; ++i) {
        unsigned r0 = srow[i];
        float p0 = sex[i] / segsum[r0];
        acc = f4fma(acc, p0, x4[(size_t)r0 * 16 + lane]);
    }
    out4[(size_t)node * 16 + lane] = acc;
}

extern "C" void kernel_launch(void* const* d_in, const int* in_sizes, int n_in,
                              void* d_out, int out_size, void* d_ws, size_t ws_size,
                              hipStream_t stream) {
    const float* x      = (const float*)d_in[0];
    const int*   row    = (const int*)d_in[1];
    const int*   col    = (const int*)d_in[2];
    const float* beta_p = (const float*)d_in[3];
    const float4* x4 = (const float4*)x;
    float4* out4 = (float4*)d_out;

    // xh (bf16 copy of x, 12.8 MB) lives in d_out scratch — read only by
    // sim_csr_kernel, which completes before gather_kernel writes d_out.
    uint2* xh2 = (uint2*)d_out;

    // workspace layout (bytes): 2*E4 + 7*S = 15.6 MB
    const size_t E4 = (size_t)N_EDGES * 4;       // 6,400,000
    const size_t S  = 400064;                    // padded N-array stride
    char* ws = (char*)d_ws;
    unsigned* srow   = (unsigned*)ws;                    // E u32 (col-sorted row ids)
    float*    sex    = (float*)(ws + E4);                // E f32 (col-sorted exp(sim))
    char* base2 = ws + 2 * E4;
    float*    segsum = (float*)(base2 + 0 * S);          // N f32
    float*    nrm    = (float*)(base2 + 1 * S);          // N f32
    unsigned* cnt    = (unsigned*)(base2 + 2 * S);       // N u32
    unsigned* incl   = (unsigned*)(base2 + 3 * S);       // N u32
    unsigned* offs   = (unsigned*)(base2 + 4 * S);       // N+1 u32
    unsigned* cursor = (unsigned*)(base2 + 5 * S);       // N u32
    unsigned* bsum   = (unsigned*)(base2 + 6 * S);       // scan block sums

    const int B = 256;
    const int nscan_blocks = (N_NODES + SCAN_B - 1) / SCAN_B;  // 391

    init_kernel<<<(N_NODES + B - 1) / B, B, 0, stream>>>(segsum, cnt);

    norm_cvt_kernel<<<(N_NODES * 16 + B - 1) / B, B, 0, stream>>>(x4, nrm, xh2);

    hist_kernel<<<(N_EDGES + B - 1) / B, B, 0, stream>>>(col, cnt);

    scan1_kernel<<<nscan_blocks, SCAN_B, 0, stream>>>(cnt, incl, bsum);
    scan2_kernel<<<1, 512, 0, stream>>>(bsum, nscan_blocks);
    scan3_kernel<<<nscan_blocks + 1, SCAN_B, 0, stream>>>(cnt, incl, bsum, offs, cursor);

    place_kernel<<<(N_EDGES + B - 1) / B, B, 0, stream>>>(row, col, cursor, srow);

    sim_csr_kernel<<<(N_NODES * 16 + B - 1) / B, B, 0, stream>>>(
        xh2, offs, srow, nrm, beta_p, segsum, sex);

    gather_kernel<<<(N_NODES * 16 + B - 1) / B, B, 0, stream>>>(x4, offs, srow, sex, segsum, out4);
}

// Round 6
// 410.301 us; speedup vs baseline: 1.0993x; 1.0993x over previous
//
#include <hip/hip_runtime.h>
#include <math.h>

#define N_NODES 100000
#define N_EDGES 1600000
#define D_FEAT 64
#define EPS 1e-7f
#define NPART 8
#define COLS_PER_PART (N_NODES / NPART)   // 12500

__device__ __forceinline__ unsigned short f32_to_bf16_rtne(float f) {
    unsigned u = __float_as_uint(f);
    unsigned rounding = 0x7FFFu + ((u >> 16) & 1u);
    return (unsigned short)((u + rounding) >> 16);
}
__device__ __forceinline__ float bf16lo_to_f32(unsigned u) {   // low 16 bits
    return __uint_as_float(u << 16);
}
__device__ __forceinline__ float bf16hi_to_f32(unsigned u) {   // high 16 bits
    return __uint_as_float(u & 0xFFFF0000u);
}
__device__ __forceinline__ float4 f4fma(float4 acc, float p, float4 a) {
    acc.x += p * a.x; acc.y += p * a.y; acc.z += p * a.z; acc.w += p * a.w;
    return acc;
}

// Zero segsum[N] and cnt[N].
__global__ void init_kernel(float* __restrict__ segsum, unsigned* __restrict__ cnt) {
    int i = blockIdx.x * blockDim.x + threadIdx.x;
    if (i < N_NODES) { cnt[i] = 0u; segsum[i] = 0.0f; }
}

// 16 lanes per node: nrm[i] = ||x[i]|| AND xh[i] = bf16(x[i]) (packed 2/uint).
__global__ void norm_cvt_kernel(const float4* __restrict__ x4, float* __restrict__ nrm,
                                uint2* __restrict__ xh2) {
    int tid = blockIdx.x * blockDim.x + threadIdx.x;
    int node = tid >> 4;
    int lane = tid & 15;
    if (node >= N_NODES) return;
    float4 v = x4[(size_t)node * 16 + lane];
    uint2 h;
    h.x = (unsigned)f32_to_bf16_rtne(v.x) | ((unsigned)f32_to_bf16_rtne(v.y) << 16);
    h.y = (unsigned)f32_to_bf16_rtne(v.z) | ((unsigned)f32_to_bf16_rtne(v.w) << 16);
    xh2[(size_t)node * 16 + lane] = h;
    float s = v.x * v.x + v.y * v.y + v.z * v.z + v.w * v.w;
    s += __shfl_xor(s, 1);
    s += __shfl_xor(s, 2);
    s += __shfl_xor(s, 4);
    s += __shfl_xor(s, 8);
    if (lane == 0) nrm[node] = sqrtf(s);
}

// Histogram of col.
__global__ void hist_kernel(const int* __restrict__ col, unsigned* __restrict__ cnt) {
    int e = blockIdx.x * blockDim.x + threadIdx.x;
    if (e >= N_EDGES) return;
    atomicAdd(&cnt[col[e]], 1u);
}

// ---- hierarchical exclusive scan over cnt[0..N) -> offs, cursor ----
#define SCAN_B 256
__global__ void scan1_kernel(const unsigned* __restrict__ cnt, unsigned* __restrict__ incl,
                             unsigned* __restrict__ bsum) {
    __shared__ unsigned sh[SCAN_B];
    int i = blockIdx.x * SCAN_B + threadIdx.x;
    unsigned v = (i < N_NODES) ? cnt[i] : 0u;
    sh[threadIdx.x] = v;
    __syncthreads();
    for (int off = 1; off < SCAN_B; off <<= 1) {
        unsigned u = (threadIdx.x >= off) ? sh[threadIdx.x - off] : 0u;
        __syncthreads();
        sh[threadIdx.x] += u;
        __syncthreads();
    }
    if (i < N_NODES) incl[i] = sh[threadIdx.x];
    if (threadIdx.x == SCAN_B - 1) bsum[blockIdx.x] = sh[SCAN_B - 1];
}

__global__ void scan2_kernel(unsigned* __restrict__ bsum, int nblocks) {
    __shared__ unsigned sh[512];
    int t = threadIdx.x;
    unsigned v = (t < nblocks) ? bsum[t] : 0u;
    sh[t] = v;
    __syncthreads();
    for (int off = 1; off < 512; off <<= 1) {
        unsigned u = (t >= off) ? sh[t - off] : 0u;
        __syncthreads();
        sh[t] += u;
        __syncthreads();
    }
    if (t < nblocks) bsum[t] = sh[t] - v;  // exclusive
}

__global__ void scan3_kernel(const unsigned* __restrict__ cnt, const unsigned* __restrict__ incl,
                             const unsigned* __restrict__ bsum, unsigned* __restrict__ offs,
                             unsigned* __restrict__ cursor) {
    int i = blockIdx.x * SCAN_B + threadIdx.x;
    if (i < N_NODES) {
        unsigned o = bsum[blockIdx.x] + incl[i] - cnt[i];
        offs[i] = o;
        cursor[i] = o;
    } else if (i == N_NODES) {
        offs[N_NODES] = N_EDGES;
    }
}

// XCD-partitioned binning: block b serves col-partition (b & 7), which the
// dispatcher round-robins onto XCD (b & 7). Each XCD scans all edges but only
// writes its own contiguous ~800KB srow region -> dirty lines accumulate in
// its private L2 instead of ping-ponging across XCDs.
__global__ void place_kernel(const int* __restrict__ row, const int* __restrict__ col,
                             unsigned* __restrict__ cursor, unsigned* __restrict__ srow) {
    int part = blockIdx.x & (NPART - 1);
    int blk  = blockIdx.x >> 3;
    int nblk = gridDim.x >> 3;
    int lo = part * COLS_PER_PART;
    int hi = lo + COLS_PER_PART;
    int stride = nblk * blockDim.x;
    for (int e = blk * blockDim.x + threadIdx.x; e < N_EDGES; e += stride) {
        int c = col[e];
        if (c >= lo && c < hi) {
            unsigned pos = atomicAdd(&cursor[c], 1u);
            srow[pos] = (unsigned)row[e];
        }
    }
}

// One 64-lane wave per node c; 4 edges per iter (16-lane sub-groups).
// c-side register-resident; sequential sex writes; segsum atomics.
__global__ void sim_csr_kernel(const uint2* __restrict__ xh2, const unsigned* __restrict__ offs,
                               const unsigned* __restrict__ srow, const float* __restrict__ nrm,
                               const float* __restrict__ beta_p, float* __restrict__ segsum,
                               float* __restrict__ sex) {
    int gtid = blockIdx.x * blockDim.x + threadIdx.x;
    int node = gtid >> 6;
    if (node >= N_NODES) return;
    int lane = threadIdx.x & 63;
    int sub = lane >> 4;      // 0..3: which edge of the 4-wide tile
    int fl  = lane & 15;      // feature chunk (8 feats as 4 bf16x2)
    uint2 hc = xh2[(size_t)node * 16 + fl];
    float c0 = bf16lo_to_f32(hc.x), c1 = bf16hi_to_f32(hc.x);
    float c2 = bf16lo_to_f32(hc.y), c3 = bf16hi_to_f32(hc.y);
    float nc = nrm[node];
    float beta = beta_p[0];
    int start = (int)offs[node];
    int end = (int)offs[node + 1];
    for (int i0 = start; i0 < end; i0 += 4) {
        int slot = i0 + sub;
        bool active = slot < end;
        int sl = active ? slot : (end - 1);
        unsigned r = srow[sl];
        uint2 a = xh2[(size_t)r * 16 + fl];
        float s = bf16lo_to_f32(a.x) * c0 + bf16hi_to_f32(a.x) * c1
                + bf16lo_to_f32(a.y) * c2 + bf16hi_to_f32(a.y) * c3;
        s += __shfl_xor(s, 1);
        s += __shfl_xor(s, 2);
        s += __shfl_xor(s, 4);
        s += __shfl_xor(s, 8);
        if (fl == 0 && active) {
            float ex = expf(beta * (s / (nrm[r] * nc + EPS)));
            sex[slot] = ex;
            atomicAdd(&segsum[r], ex);
        }
    }
}

// One 64-lane wave per node: out[n] = sum over incoming edges of
// (ex/segsum[row]) * x[row]; 4 edges per iter, cross-sub reduce at the end.
__global__ void gather_kernel(const float4* __restrict__ x4, const unsigned* __restrict__ offs,
                              const unsigned* __restrict__ srow, const float* __restrict__ sex,
                              const float* __restrict__ segsum, float4* __restrict__ out4) {
    int gtid = blockIdx.x * blockDim.x + threadIdx.x;
    int node = gtid >> 6;
    if (node >= N_NODES) return;
    int lane = threadIdx.x & 63;
    int sub = lane >> 4;
    int fl  = lane & 15;
    int start = (int)offs[node];
    int end = (int)offs[node + 1];
    float4 acc = make_float4(0.f, 0.f, 0.f, 0.f);
    for (int i0 = start; i0 < end; i0 += 4) {
        int slot = i0 + sub;
        bool active = slot < end;
        int sl = active ? slot : (end - 1);
        unsigned r = srow[sl];
        float p = active ? (sex[sl] / segsum[r]) : 0.0f;
        float4 a = x4[(size_t)r * 16 + fl];
        acc = f4fma(acc, p, a);
    }
    // reduce across the 4 sub-groups (lanes fl, fl+16, fl+32, fl+48)
    acc.x += __shfl_xor(acc.x, 16);
    acc.y += __shfl_xor(acc.y, 16);
    acc.z += __shfl_xor(acc.z, 16);
    acc.w += __shfl_xor(acc.w, 16);
    acc.x += __shfl_xor(acc.x, 32);
    acc.y += __shfl_xor(acc.y, 32);
    acc.z += __shfl_xor(acc.z, 32);
    acc.w += __shfl_xor(acc.w, 32);
    if (sub == 0) out4[(size_t)node * 16 + fl] = acc;
}

extern "C" void kernel_launch(void* const* d_in, const int* in_sizes, int n_in,
                              void* d_out, int out_size, void* d_ws, size_t ws_size,
                              hipStream_t stream) {
    const float* x      = (const float*)d_in[0];
    const int*   row    = (const int*)d_in[1];
    const int*   col    = (const int*)d_in[2];
    const float* beta_p = (const float*)d_in[3];
    const float4* x4 = (const float4*)x;
    float4* out4 = (float4*)d_out;

    // xh (bf16 copy of x, 12.8 MB) lives in d_out scratch — read only by
    // sim_csr_kernel, which completes before gather_kernel writes d_out.
    uint2* xh2 = (uint2*)d_out;

    // workspace layout (bytes): 2*E4 + 7*S = 15.6 MB
    const size_t E4 = (size_t)N_EDGES * 4;       // 6,400,000
    const size_t S  = 400064;                    // padded N-array stride
    char* ws = (char*)d_ws;
    unsigned* srow   = (unsigned*)ws;                    // E u32 (col-sorted row ids)
    float*    sex    = (float*)(ws + E4);                // E f32 (col-sorted exp(sim))
    char* base2 = ws + 2 * E4;
    float*    segsum = (float*)(base2 + 0 * S);          // N f32
    float*    nrm    = (float*)(base2 + 1 * S);          // N f32
    unsigned* cnt    = (unsigned*)(base2 + 2 * S);       // N u32
    unsigned* incl   = (unsigned*)(base2 + 3 * S);       // N u32
    unsigned* offs   = (unsigned*)(base2 + 4 * S);       // N+1 u32
    unsigned* cursor = (unsigned*)(base2 + 5 * S);       // N u32
    unsigned* bsum   = (unsigned*)(base2 + 6 * S);       // scan block sums

    const int B = 256;
    const int nscan_blocks = (N_NODES + SCAN_B - 1) / SCAN_B;  // 391

    init_kernel<<<(N_NODES + B - 1) / B, B, 0, stream>>>(segsum, cnt);

    norm_cvt_kernel<<<(N_NODES * 16 + B - 1) / B, B, 0, stream>>>(x4, nrm, xh2);

    hist_kernel<<<(N_EDGES + B - 1) / B, B, 0, stream>>>(col, cnt);

    scan1_kernel<<<nscan_blocks, SCAN_B, 0, stream>>>(cnt, incl, bsum);
    scan2_kernel<<<1, 512, 0, stream>>>(bsum, nscan_blocks);
    scan3_kernel<<<nscan_blocks + 1, SCAN_B, 0, stream>>>(cnt, incl, bsum, offs, cursor);

    // 2048 blocks = 256 per partition; partition p = blockIdx & 7 -> XCD p.
    place_kernel<<<2048, B, 0, stream>>>(row, col, cursor, srow);

    int node_wave_grid = (N_NODES * 64) / B;   // 25000 blocks, 4 waves each
    sim_csr_kernel<<<node_wave_grid, B, 0, stream>>>(
        xh2, offs, srow, nrm, beta_p, segsum, sex);

    gather_kernel<<<node_wave_grid, B, 0, stream>>>(x4, offs, srow, sex, segsum, out4);
}

// Round 7
// 370.953 us; speedup vs baseline: 1.2159x; 1.1061x over previous
//
#include <hip/hip_runtime.h>
#include <math.h>

#define N_NODES 100000
#define N_EDGES 1600000
#define D_FEAT 64
#define EPS 1e-7f
#define NPART 8
#define COLS_PER_PART (N_NODES / NPART)   // 12500
#define QSCALE 12000.0f                   // ex in (0.367, 2.719) -> q in (4407, 32628) < 2^15
#define QINV (1.0f / 12000.0f)

typedef _Float16 h2 __attribute__((ext_vector_type(2)));

__device__ __forceinline__ unsigned pack2h(float a, float b) {
    h2 h;
    h.x = (_Float16)a;
    h.y = (_Float16)b;
    return __builtin_bit_cast(unsigned, h);
}

__device__ __forceinline__ float dot2acc(unsigned a, unsigned b, float c) {
#if __has_builtin(__builtin_amdgcn_fdot2)
    return __builtin_amdgcn_fdot2(__builtin_bit_cast(h2, a),
                                  __builtin_bit_cast(h2, b), c, false);
#else
    h2 ha = __builtin_bit_cast(h2, a), hb = __builtin_bit_cast(h2, b);
    return c + (float)ha.x * (float)hb.x + (float)ha.y * (float)hb.y;
#endif
}

__device__ __forceinline__ void fma2h(unsigned ab, float p, float& x, float& y) {
    h2 h = __builtin_bit_cast(h2, ab);
    x += p * (float)h.x;
    y += p * (float)h.y;
}

// Zero segsum[N] and cnt[N].
__global__ void init_kernel(float* __restrict__ segsum, unsigned* __restrict__ cnt) {
    int i = blockIdx.x * blockDim.x + threadIdx.x;
    if (i < N_NODES) { cnt[i] = 0u; segsum[i] = 0.0f; }
}

// 16 lanes per node: nrm[i] = ||x[i]|| AND xh[i] = f16(x[i]) (packed 2/uint).
__global__ void norm_cvt_kernel(const float4* __restrict__ x4, float* __restrict__ nrm,
                                uint2* __restrict__ xh2) {
    int tid = blockIdx.x * blockDim.x + threadIdx.x;
    int node = tid >> 4;
    int lane = tid & 15;
    if (node >= N_NODES) return;
    float4 v = x4[(size_t)node * 16 + lane];
    uint2 h;
    h.x = pack2h(v.x, v.y);
    h.y = pack2h(v.z, v.w);
    xh2[(size_t)node * 16 + lane] = h;
    float s = v.x * v.x + v.y * v.y + v.z * v.z + v.w * v.w;
    s += __shfl_xor(s, 1);
    s += __shfl_xor(s, 2);
    s += __shfl_xor(s, 4);
    s += __shfl_xor(s, 8);
    if (lane == 0) nrm[node] = sqrtf(s);
}

// XCD-partitioned histogram of col (same locality trick as place_kernel).
__global__ void hist_kernel(const int* __restrict__ col, unsigned* __restrict__ cnt) {
    int part = blockIdx.x & (NPART - 1);
    int blk  = blockIdx.x >> 3;
    int nblk = gridDim.x >> 3;
    int lo = part * COLS_PER_PART;
    int hi = lo + COLS_PER_PART;
    int stride = nblk * blockDim.x;
    for (int e = blk * blockDim.x + threadIdx.x; e < N_EDGES; e += stride) {
        int c = col[e];
        if (c >= lo && c < hi) atomicAdd(&cnt[c], 1u);
    }
}

// ---- hierarchical exclusive scan over cnt[0..N) -> offs, cursor ----
#define SCAN_B 256
__global__ void scan1_kernel(const unsigned* __restrict__ cnt, unsigned* __restrict__ incl,
                             unsigned* __restrict__ bsum) {
    __shared__ unsigned sh[SCAN_B];
    int i = blockIdx.x * SCAN_B + threadIdx.x;
    unsigned v = (i < N_NODES) ? cnt[i] : 0u;
    sh[threadIdx.x] = v;
    __syncthreads();
    for (int off = 1; off < SCAN_B; off <<= 1) {
        unsigned u = (threadIdx.x >= off) ? sh[threadIdx.x - off] : 0u;
        __syncthreads();
        sh[threadIdx.x] += u;
        __syncthreads();
    }
    if (i < N_NODES) incl[i] = sh[threadIdx.x];
    if (threadIdx.x == SCAN_B - 1) bsum[blockIdx.x] = sh[SCAN_B - 1];
}

__global__ void scan2_kernel(unsigned* __restrict__ bsum, int nblocks) {
    __shared__ unsigned sh[512];
    int t = threadIdx.x;
    unsigned v = (t < nblocks) ? bsum[t] : 0u;
    sh[t] = v;
    __syncthreads();
    for (int off = 1; off < 512; off <<= 1) {
        unsigned u = (t >= off) ? sh[t - off] : 0u;
        __syncthreads();
        sh[t] += u;
        __syncthreads();
    }
    if (t < nblocks) bsum[t] = sh[t] - v;  // exclusive
}

__global__ void scan3_kernel(const unsigned* __restrict__ cnt, const unsigned* __restrict__ incl,
                             const unsigned* __restrict__ bsum, unsigned* __restrict__ offs,
                             unsigned* __restrict__ cursor) {
    int i = blockIdx.x * SCAN_B + threadIdx.x;
    if (i < N_NODES) {
        unsigned o = bsum[blockIdx.x] + incl[i] - cnt[i];
        offs[i] = o;
        cursor[i] = o;
    } else if (i == N_NODES) {
        offs[N_NODES] = N_EDGES;
    }
}

// XCD-partitioned binning: block b serves col-partition (b & 7). Writes
// pay[pos] = row << 15 (low 15 bits filled by sim_csr_kernel later).
__global__ void place_kernel(const int* __restrict__ row, const int* __restrict__ col,
                             unsigned* __restrict__ cursor, unsigned* __restrict__ pay) {
    int part = blockIdx.x & (NPART - 1);
    int blk  = blockIdx.x >> 3;
    int nblk = gridDim.x >> 3;
    int lo = part * COLS_PER_PART;
    int hi = lo + COLS_PER_PART;
    int stride = nblk * blockDim.x;
    for (int e = blk * blockDim.x + threadIdx.x; e < N_EDGES; e += stride) {
        int c = col[e];
        if (c >= lo && c < hi) {
            unsigned pos = atomicAdd(&cursor[c], 1u);
            pay[pos] = (unsigned)row[e] << 15;
        }
    }
}

// One 64-lane wave per node c; 8 edges per iter (8-lane sub-groups, uint4 f16
// loads, v_dot2 accumulate). Writes q15(ex) into pay low bits (in-place,
// sequential), accumulates segsum[row].
__global__ void sim_csr_kernel(const uint4* __restrict__ xh4, const unsigned* __restrict__ offs,
                               unsigned* __restrict__ pay, const float* __restrict__ nrm,
                               const float* __restrict__ beta_p, float* __restrict__ segsum) {
    int gtid = blockIdx.x * blockDim.x + threadIdx.x;
    int node = gtid >> 6;
    if (node >= N_NODES) return;
    int lane = threadIdx.x & 63;
    int sub = lane >> 3;      // 0..7: which edge of the 8-wide tile
    int fl  = lane & 7;       // feature chunk: 8 f16 per lane
    uint4 hc = xh4[(size_t)node * 8 + fl];
    float nc = nrm[node];
    float beta = beta_p[0];
    int start = (int)offs[node];
    int end = (int)offs[node + 1];
    for (int i0 = start; i0 < end; i0 += 8) {
        int slot = i0 + sub;
        bool active = slot < end;
        int sl = active ? slot : (end - 1);
        unsigned pv = pay[sl];
        unsigned r = pv >> 15;
        uint4 a = xh4[(size_t)r * 8 + fl];
        float s = 0.0f;
        s = dot2acc(a.x, hc.x, s);
        s = dot2acc(a.y, hc.y, s);
        s = dot2acc(a.z, hc.z, s);
        s = dot2acc(a.w, hc.w, s);
        s += __shfl_xor(s, 1);
        s += __shfl_xor(s, 2);
        s += __shfl_xor(s, 4);
        if (fl == 0 && active) {
            float ex = expf(beta * (s / (nrm[r] * nc + EPS)));
            unsigned q = (unsigned)(ex * QSCALE + 0.5f);
            pay[slot] = pv | q;
            atomicAdd(&segsum[r], (float)q * QINV);
        }
    }
}

// One 64-lane wave per node: out[n] = sum over incoming edges of
// (ex/segsum[row]) * x[row] with f16 x; 8 edges per iter; cross-sub reduce.
__global__ void gather_kernel(const uint4* __restrict__ xh4, const unsigned* __restrict__ offs,
                              const unsigned* __restrict__ pay, const float* __restrict__ segsum,
                              float4* __restrict__ out4) {
    int gtid = blockIdx.x * blockDim.x + threadIdx.x;
    int node = gtid >> 6;
    if (node >= N_NODES) return;
    int lane = threadIdx.x & 63;
    int sub = lane >> 3;
    int fl  = lane & 7;
    int start = (int)offs[node];
    int end = (int)offs[node + 1];
    float a0 = 0.f, a1 = 0.f, a2 = 0.f, a3 = 0.f;
    float a4 = 0.f, a5 = 0.f, a6 = 0.f, a7 = 0.f;
    for (int i0 = start; i0 < end; i0 += 8) {
        int slot = i0 + sub;
        bool active = slot < end;
        int sl = active ? slot : (end - 1);
        unsigned pv = pay[sl];
        unsigned r = pv >> 15;
        float ex = (float)(pv & 0x7FFFu) * QINV;
        float p = active ? (ex / segsum[r]) : 0.0f;
        uint4 a = xh4[(size_t)r * 8 + fl];
        fma2h(a.x, p, a0, a1);
        fma2h(a.y, p, a2, a3);
        fma2h(a.z, p, a4, a5);
        fma2h(a.w, p, a6, a7);
    }
    // reduce across the 8 sub-groups (stride 8, 16, 32)
    #pragma unroll
    for (int m = 8; m <= 32; m <<= 1) {
        a0 += __shfl_xor(a0, m);
        a1 += __shfl_xor(a1, m);
        a2 += __shfl_xor(a2, m);
        a3 += __shfl_xor(a3, m);
        a4 += __shfl_xor(a4, m);
        a5 += __shfl_xor(a5, m);
        a6 += __shfl_xor(a6, m);
        a7 += __shfl_xor(a7, m);
    }
    if (sub == 0) {
        out4[(size_t)node * 16 + fl * 2]     = make_float4(a0, a1, a2, a3);
        out4[(size_t)node * 16 + fl * 2 + 1] = make_float4(a4, a5, a6, a7);
    }
}

extern "C" void kernel_launch(void* const* d_in, const int* in_sizes, int n_in,
                              void* d_out, int out_size, void* d_ws, size_t ws_size,
                              hipStream_t stream) {
    const float* x      = (const float*)d_in[0];
    const int*   row    = (const int*)d_in[1];
    const int*   col    = (const int*)d_in[2];
    const float* beta_p = (const float*)d_in[3];
    const float4* x4 = (const float4*)x;
    float4* out4 = (float4*)d_out;

    // workspace layout (bytes): E4 + 12.8MB + 7*S = 22.0 MB (== round-3 proven)
    const size_t E4 = (size_t)N_EDGES * 4;       // 6,400,000 (16-aligned)
    const size_t XH = (size_t)N_NODES * D_FEAT * 2;  // 12,800,000 f16 copy of x
    const size_t S  = 400064;                    // padded N-array stride
    char* ws = (char*)d_ws;
    unsigned* pay    = (unsigned*)ws;                    // E u32: (row<<15)|q15(ex)
    uint2*    xh2    = (uint2*)(ws + E4);                // f16 x, write view
    const uint4* xh4 = (const uint4*)(ws + E4);          // f16 x, read view
    char* base2 = ws + E4 + XH;
    float*    segsum = (float*)(base2 + 0 * S);          // N f32
    float*    nrm    = (float*)(base2 + 1 * S);          // N f32
    unsigned* cnt    = (unsigned*)(base2 + 2 * S);       // N u32
    unsigned* incl   = (unsigned*)(base2 + 3 * S);       // N u32
    unsigned* offs   = (unsigned*)(base2 + 4 * S);       // N+1 u32
    unsigned* cursor = (unsigned*)(base2 + 5 * S);       // N u32
    unsigned* bsum   = (unsigned*)(base2 + 6 * S);       // scan block sums

    const int B = 256;
    const int nscan_blocks = (N_NODES + SCAN_B - 1) / SCAN_B;  // 391

    init_kernel<<<(N_NODES + B - 1) / B, B, 0, stream>>>(segsum, cnt);

    norm_cvt_kernel<<<(N_NODES * 16 + B - 1) / B, B, 0, stream>>>(x4, nrm, xh2);

    hist_kernel<<<2048, B, 0, stream>>>(col, cnt);

    scan1_kernel<<<nscan_blocks, SCAN_B, 0, stream>>>(cnt, incl, bsum);
    scan2_kernel<<<1, 512, 0, stream>>>(bsum, nscan_blocks);
    scan3_kernel<<<nscan_blocks + 1, SCAN_B, 0, stream>>>(cnt, incl, bsum, offs, cursor);

    place_kernel<<<2048, B, 0, stream>>>(row, col, cursor, pay);

    int node_wave_grid = (N_NODES * 64) / B;   // 25000 blocks, 4 waves each
    sim_csr_kernel<<<node_wave_grid, B, 0, stream>>>(xh4, offs, pay, nrm, beta_p, segsum);

    gather_kernel<<<node_wave_grid, B, 0, stream>>>(xh4, offs, pay, segsum, out4);
}

// Round 8
// 356.914 us; speedup vs baseline: 1.2637x; 1.0393x over previous
//
#include <hip/hip_runtime.h>
#include <math.h>

#define N_NODES 100000
#define N_EDGES 1600000
#define D_FEAT 64
#define EPS 1e-7f
#define NPART 8
#define COLS_PER_PART (N_NODES / NPART)   // 12500
#define QSCALE 12000.0f                   // ex in (0.367, 2.722) -> q in (4407, 32660) < 2^15
#define QINV (1.0f / 12000.0f)

typedef _Float16 h2 __attribute__((ext_vector_type(2)));

__device__ __forceinline__ unsigned pack2h(float a, float b) {
    h2 h;
    h.x = (_Float16)a;
    h.y = (_Float16)b;
    return __builtin_bit_cast(unsigned, h);
}

__device__ __forceinline__ float dot2acc(unsigned a, unsigned b, float c) {
#if __has_builtin(__builtin_amdgcn_fdot2)
    return __builtin_amdgcn_fdot2(__builtin_bit_cast(h2, a),
                                  __builtin_bit_cast(h2, b), c, false);
#else
    h2 ha = __builtin_bit_cast(h2, a), hb = __builtin_bit_cast(h2, b);
    return c + (float)ha.x * (float)hb.x + (float)ha.y * (float)hb.y;
#endif
}

__device__ __forceinline__ void fma2h(unsigned ab, float p, float& x, float& y) {
    h2 h = __builtin_bit_cast(h2, ab);
    x += p * (float)h.x;
    y += p * (float)h.y;
}

// Fused: blocks [0, norm_blocks) do norm+f16-convert (16 lanes/node);
// blocks [norm_blocks, ...) do the XCD-partitioned col histogram.
__global__ void prep_kernel(const float4* __restrict__ x4, float* __restrict__ nrm,
                            uint2* __restrict__ xh2, const int* __restrict__ col,
                            unsigned* __restrict__ cnt, int norm_blocks) {
    if ((int)blockIdx.x < norm_blocks) {
        int tid = blockIdx.x * blockDim.x + threadIdx.x;
        int node = tid >> 4;
        int lane = tid & 15;
        if (node >= N_NODES) return;
        float4 v = x4[(size_t)node * 16 + lane];
        uint2 h;
        h.x = pack2h(v.x, v.y);
        h.y = pack2h(v.z, v.w);
        xh2[(size_t)node * 16 + lane] = h;
        float s = v.x * v.x + v.y * v.y + v.z * v.z + v.w * v.w;
        s += __shfl_xor(s, 1);
        s += __shfl_xor(s, 2);
        s += __shfl_xor(s, 4);
        s += __shfl_xor(s, 8);
        if (lane == 0) nrm[node] = sqrtf(s);
    } else {
        int hb = blockIdx.x - norm_blocks;
        int part = hb & (NPART - 1);           // consistent partition->XCD bijection
        int blk = hb >> 3;
        int nblk = (gridDim.x - norm_blocks) >> 3;
        int lo = part * COLS_PER_PART;
        int hi = lo + COLS_PER_PART;
        int stride = nblk * blockDim.x;
        for (int e = blk * blockDim.x + threadIdx.x; e < N_EDGES; e += stride) {
            int c = col[e];
            if (c >= lo && c < hi) atomicAdd(&cnt[c], 1u);
        }
    }
}

// ---- hierarchical exclusive scan over cnt[0..N) -> offs, cursor ----
#define SCAN_B 256
__global__ void scan1_kernel(const unsigned* __restrict__ cnt, unsigned* __restrict__ incl,
                             unsigned* __restrict__ bsum) {
    __shared__ unsigned sh[SCAN_B];
    int i = blockIdx.x * SCAN_B + threadIdx.x;
    unsigned v = (i < N_NODES) ? cnt[i] : 0u;
    sh[threadIdx.x] = v;
    __syncthreads();
    for (int off = 1; off < SCAN_B; off <<= 1) {
        unsigned u = (threadIdx.x >= off) ? sh[threadIdx.x - off] : 0u;
        __syncthreads();
        sh[threadIdx.x] += u;
        __syncthreads();
    }
    if (i < N_NODES) incl[i] = sh[threadIdx.x];
    if (threadIdx.x == SCAN_B - 1) bsum[blockIdx.x] = sh[SCAN_B - 1];
}

__global__ void scan2_kernel(unsigned* __restrict__ bsum, int nblocks) {
    __shared__ unsigned sh[512];
    int t = threadIdx.x;
    unsigned v = (t < nblocks) ? bsum[t] : 0u;
    sh[t] = v;
    __syncthreads();
    for (int off = 1; off < 512; off <<= 1) {
        unsigned u = (t >= off) ? sh[t - off] : 0u;
        __syncthreads();
        sh[t] += u;
        __syncthreads();
    }
    if (t < nblocks) bsum[t] = sh[t] - v;  // exclusive
}

__global__ void scan3_kernel(const unsigned* __restrict__ cnt, const unsigned* __restrict__ incl,
                             const unsigned* __restrict__ bsum, unsigned* __restrict__ offs,
                             unsigned* __restrict__ cursor) {
    int i = blockIdx.x * SCAN_B + threadIdx.x;
    if (i < N_NODES) {
        unsigned o = bsum[blockIdx.x] + incl[i] - cnt[i];
        offs[i] = o;
        cursor[i] = o;
    } else if (i == N_NODES) {
        offs[N_NODES] = N_EDGES;
    }
}

// XCD-partitioned binning: block b serves col-partition (b & 7). Writes
// pay[pos] = row << 15 (low 15 bits filled by sim_csr_kernel later).
__global__ void place_kernel(const int* __restrict__ row, const int* __restrict__ col,
                             unsigned* __restrict__ cursor, unsigned* __restrict__ pay) {
    int part = blockIdx.x & (NPART - 1);
    int blk  = blockIdx.x >> 3;
    int nblk = gridDim.x >> 3;
    int lo = part * COLS_PER_PART;
    int hi = lo + COLS_PER_PART;
    int stride = nblk * blockDim.x;
    for (int e = blk * blockDim.x + threadIdx.x; e < N_EDGES; e += stride) {
        int c = col[e];
        if (c >= lo && c < hi) {
            unsigned pos = atomicAdd(&cursor[c], 1u);
            pay[pos] = (unsigned)row[e] << 15;
        }
    }
}

// One 64-lane wave per node c; 16 edges per iter (8 sub-groups x 2 slots),
// all tail loads predicated (no wasted gathers). q15(ex) ORed into pay.
__global__ void sim_csr_kernel(const uint4* __restrict__ xh4, const unsigned* __restrict__ offs,
                               unsigned* __restrict__ pay, const float* __restrict__ nrm,
                               const float* __restrict__ beta_p, float* __restrict__ segsum) {
    int gtid = blockIdx.x * blockDim.x + threadIdx.x;
    int node = gtid >> 6;
    if (node >= N_NODES) return;
    int lane = threadIdx.x & 63;
    int sub = lane >> 3;      // 0..7
    int fl  = lane & 7;       // feature chunk: 8 f16 per lane
    uint4 hc = xh4[(size_t)node * 8 + fl];
    float nc = nrm[node];
    float beta = beta_p[0];
    int start = (int)offs[node];
    int end = (int)offs[node + 1];
    for (int i0 = start; i0 < end; i0 += 16) {
        int s0 = i0 + sub;
        int s1 = s0 + 8;
        bool a0 = s0 < end, a1 = s1 < end;
        unsigned pv0 = 0u, pv1 = 0u;
        uint4 A0 = make_uint4(0u, 0u, 0u, 0u);
        uint4 A1 = make_uint4(0u, 0u, 0u, 0u);
        if (a0) pv0 = pay[s0];
        if (a1) pv1 = pay[s1];
        if (a0) A0 = xh4[(size_t)(pv0 >> 15) * 8 + fl];
        if (a1) A1 = xh4[(size_t)(pv1 >> 15) * 8 + fl];
        float d0 = 0.0f, d1 = 0.0f;
        d0 = dot2acc(A0.x, hc.x, d0); d1 = dot2acc(A1.x, hc.x, d1);
        d0 = dot2acc(A0.y, hc.y, d0); d1 = dot2acc(A1.y, hc.y, d1);
        d0 = dot2acc(A0.z, hc.z, d0); d1 = dot2acc(A1.z, hc.z, d1);
        d0 = dot2acc(A0.w, hc.w, d0); d1 = dot2acc(A1.w, hc.w, d1);
        d0 += __shfl_xor(d0, 1);  d1 += __shfl_xor(d1, 1);
        d0 += __shfl_xor(d0, 2);  d1 += __shfl_xor(d1, 2);
        d0 += __shfl_xor(d0, 4);  d1 += __shfl_xor(d1, 4);
        if (fl == 0) {
            if (a0) {
                unsigned r = pv0 >> 15;
                float ex = expf(beta * (d0 / (nrm[r] * nc + EPS)));
                unsigned q = (unsigned)(ex * QSCALE + 0.5f);
                pay[s0] = pv0 | q;
                atomicAdd(&segsum[r], (float)q * QINV);
            }
            if (a1) {
                unsigned r = pv1 >> 15;
                float ex = expf(beta * (d1 / (nrm[r] * nc + EPS)));
                unsigned q = (unsigned)(ex * QSCALE + 0.5f);
                pay[s1] = pv1 | q;
                atomicAdd(&segsum[r], (float)q * QINV);
            }
        }
    }
}

// One 64-lane wave per node: out[n] = sum of (ex/segsum[row]) * x[row] (f16 x);
// 16 edges per iter, predicated loads, cross-sub reduce at the end.
__global__ void gather_kernel(const uint4* __restrict__ xh4, const unsigned* __restrict__ offs,
                              const unsigned* __restrict__ pay, const float* __restrict__ segsum,
                              float4* __restrict__ out4) {
    int gtid = blockIdx.x * blockDim.x + threadIdx.x;
    int node = gtid >> 6;
    if (node >= N_NODES) return;
    int lane = threadIdx.x & 63;
    int sub = lane >> 3;
    int fl  = lane & 7;
    int start = (int)offs[node];
    int end = (int)offs[node + 1];
    float a0 = 0.f, a1 = 0.f, a2 = 0.f, a3 = 0.f;
    float a4 = 0.f, a5 = 0.f, a6 = 0.f, a7 = 0.f;
    for (int i0 = start; i0 < end; i0 += 16) {
        int s0 = i0 + sub;
        int s1 = s0 + 8;
        bool ac0 = s0 < end, ac1 = s1 < end;
        unsigned pv0 = 0u, pv1 = 0u;
        uint4 A0 = make_uint4(0u, 0u, 0u, 0u);
        uint4 A1 = make_uint4(0u, 0u, 0u, 0u);
        float p0 = 0.0f, p1 = 0.0f;
        if (ac0) pv0 = pay[s0];
        if (ac1) pv1 = pay[s1];
        if (ac0) {
            unsigned r = pv0 >> 15;
            A0 = xh4[(size_t)r * 8 + fl];
            p0 = (float)(pv0 & 0x7FFFu) * QINV / segsum[r];
        }
        if (ac1) {
            unsigned r = pv1 >> 15;
            A1 = xh4[(size_t)r * 8 + fl];
            p1 = (float)(pv1 & 0x7FFFu) * QINV / segsum[r];
        }
        fma2h(A0.x, p0, a0, a1); fma2h(A1.x, p1, a0, a1);
        fma2h(A0.y, p0, a2, a3); fma2h(A1.y, p1, a2, a3);
        fma2h(A0.z, p0, a4, a5); fma2h(A1.z, p1, a4, a5);
        fma2h(A0.w, p0, a6, a7); fma2h(A1.w, p1, a6, a7);
    }
    #pragma unroll
    for (int m = 8; m <= 32; m <<= 1) {
        a0 += __shfl_xor(a0, m);
        a1 += __shfl_xor(a1, m);
        a2 += __shfl_xor(a2, m);
        a3 += __shfl_xor(a3, m);
        a4 += __shfl_xor(a4, m);
        a5 += __shfl_xor(a5, m);
        a6 += __shfl_xor(a6, m);
        a7 += __shfl_xor(a7, m);
    }
    if (sub == 0) {
        out4[(size_t)node * 16 + fl * 2]     = make_float4(a0, a1, a2, a3);
        out4[(size_t)node * 16 + fl * 2 + 1] = make_float4(a4, a5, a6, a7);
    }
}

extern "C" void kernel_launch(void* const* d_in, const int* in_sizes, int n_in,
                              void* d_out, int out_size, void* d_ws, size_t ws_size,
                              hipStream_t stream) {
    const float* x      = (const float*)d_in[0];
    const int*   row    = (const int*)d_in[1];
    const int*   col    = (const int*)d_in[2];
    const float* beta_p = (const float*)d_in[3];
    const float4* x4 = (const float4*)x;
    float4* out4 = (float4*)d_out;

    // workspace layout (bytes): E4 + 12.8MB + 7*S = 22.0 MB
    const size_t E4 = (size_t)N_EDGES * 4;       // 6,400,000 (16-aligned)
    const size_t XH = (size_t)N_NODES * D_FEAT * 2;  // 12,800,000 f16 copy of x
    const size_t S  = 400064;                    // padded N-array stride
    char* ws = (char*)d_ws;
    unsigned* pay    = (unsigned*)ws;                    // E u32: (row<<15)|q15(ex)
    uint2*    xh2    = (uint2*)(ws + E4);                // f16 x, write view
    const uint4* xh4 = (const uint4*)(ws + E4);          // f16 x, read view
    char* base2 = ws + E4 + XH;
    float*    segsum = (float*)(base2 + 0 * S);          // N f32   (zeroed by memset)
    unsigned* cnt    = (unsigned*)(base2 + 1 * S);       // N u32   (zeroed by memset)
    float*    nrm    = (float*)(base2 + 2 * S);          // N f32
    unsigned* incl   = (unsigned*)(base2 + 3 * S);       // N u32
    unsigned* offs   = (unsigned*)(base2 + 4 * S);       // N+1 u32
    unsigned* cursor = (unsigned*)(base2 + 5 * S);       // N u32
    unsigned* bsum   = (unsigned*)(base2 + 6 * S);       // scan block sums

    const int B = 256;
    const int nscan_blocks = (N_NODES + SCAN_B - 1) / SCAN_B;  // 391

    // zero segsum + cnt in one async memset (adjacent in layout)
    hipMemsetAsync(base2, 0, 2 * S, stream);

    const int norm_blocks = (N_NODES * 16 + B - 1) / B;   // 6250
    const int hist_blocks = 2048;
    prep_kernel<<<norm_blocks + hist_blocks, B, 0, stream>>>(x4, nrm, xh2, col, cnt, norm_blocks);

    scan1_kernel<<<nscan_blocks, SCAN_B, 0, stream>>>(cnt, incl, bsum);
    scan2_kernel<<<1, 512, 0, stream>>>(bsum, nscan_blocks);
    scan3_kernel<<<nscan_blocks + 1, SCAN_B, 0, stream>>>(cnt, incl, bsum, offs, cursor);

    place_kernel<<<2048, B, 0, stream>>>(row, col, cursor, pay);

    int node_wave_grid = (N_NODES * 64) / B;   // 25000 blocks, 4 waves each
    sim_csr_kernel<<<node_wave_grid, B, 0, stream>>>(xh4, offs, pay, nrm, beta_p, segsum);

    gather_kernel<<<node_wave_grid, B, 0, stream>>>(xh4, offs, pay, segsum, out4);
}